// Round 1
// baseline (687.608 us; speedup 1.0000x reference)
//
#include <hip/hip_runtime.h>
#include <math.h>

// N=B*H*W=8192 tokens, K=8192 codes, D=256 dims.
// Numerics (bit-exact vs np in rounds 2-3): first-occurrence argmax over k of
//   s = fl(g - fl(A_n - M_nk)), A_n = numpy-pairwise fp32 sum of fl(f^2),
//   M = (2f)@W^T. Round 4: 4-pass split-bf16 MFMA (hi/mid), global_load_lds
//   staging, XOR-swizzled unpadded LDS, kc-loop.
// Round 5: 2-phase pipeline (T3/T4): double-buffered LDS, stage(next) issued
//   before compute, single inline vmcnt(0)+s_barrier per phase (no compiler
//   full-drain __syncthreads in the hot loop), gumbel prefetched one kc ahead
//   into VGPRs, s_setprio(1) around the MFMA cluster (T5). MFMA order and all
//   fp rounding identical to round 4 -> bit-identical outputs.

typedef __attribute__((ext_vector_type(8))) short bf16x8;
typedef __attribute__((ext_vector_type(4))) float floatx4;

__device__ __forceinline__ float sq025(float q) {
  return __fmul_rn(__fmul_rn(q, q), 0.25f);
}
__device__ __forceinline__ unsigned short bf16_rne(float x) {
  unsigned int u = __float_as_uint(x);
  return (unsigned short)((u + 0x7FFFu + ((u >> 16) & 1u)) >> 16);
}
__device__ __forceinline__ float bf16f(unsigned short h) {
  return __uint_as_float(((unsigned int)h) << 16);
}
__device__ __forceinline__ void glds16(const void* g, void* l) {
  __builtin_amdgcn_global_load_lds(
      (const __attribute__((address_space(1))) unsigned int*)g,
      (__attribute__((address_space(3))) unsigned int*)l, 16, 0, 0);
}

// ---- prep A: z_e (NCHW) -> a_hi/a_mid (split of q=2z, [n][d]) + Arow ----
__global__ void vq_prep_a(const float* __restrict__ z_e,
                          unsigned short* __restrict__ a_hi,
                          unsigned short* __restrict__ a_mid,
                          float* __restrict__ Arow) {
  __shared__ float tile[256][36];
  const int bx = blockIdx.x;  // b*32 + h
  const int b = bx >> 5, h = bx & 31;
  const int tid = threadIdx.x;
  const int w = tid & 31, dg = tid >> 5;
  const size_t zbase = (size_t)b * (256 * 1024) + (size_t)h * 32;
#pragma unroll 4
  for (int it = 0; it < 32; ++it) {
    const int d = dg * 32 + it;
    tile[d][w] = 2.0f * z_e[zbase + (size_t)d * 1024 + w];  // q = 2f, exact
  }
  __syncthreads();
  const int n0 = bx * 32;
#pragma unroll 4
  for (int w2 = 0; w2 < 32; ++w2) {
    const float q = tile[tid][w2];
    const unsigned short hh = bf16_rne(q);
    const float r1 = __fsub_rn(q, bf16f(hh));
    a_hi[(size_t)(n0 + w2) * 256 + tid] = hh;
    a_mid[(size_t)(n0 + w2) * 256 + tid] = bf16_rne(r1);
  }
  // numpy-pairwise ||f||^2 from q=2f (verified bit-exact in r2/r3)
  const int tg = tid >> 3, j = tid & 7;
  float halfs[2];
#pragma unroll
  for (int hf = 0; hf < 2; ++hf) {
    float r = sq025(tile[hf * 128 + j][tg]);
#pragma unroll
    for (int i = 1; i < 16; ++i)
      r = __fadd_rn(r, sq025(tile[hf * 128 + 8 * i + j][tg]));
    const float t2 = __fadd_rn(r, __shfl_xor(r, 1, 64));
    const float t4 = __fadd_rn(t2, __shfl_xor(t2, 2, 64));
    halfs[hf] = __fadd_rn(t4, __shfl_xor(t4, 4, 64));
  }
  if (j == 0) Arow[n0 + tg] = __fadd_rn(halfs[0], halfs[1]);
}

// ---- prep W: weight -> w_hi/w_mid ----
__global__ void vq_prep_w(const float* __restrict__ weight,
                          unsigned short* __restrict__ w_hi,
                          unsigned short* __restrict__ w_mid) {
  const int u = blockIdx.x * 256 + threadIdx.x;  // float4 idx, 524288 total
  const float4 v = ((const float4*)weight)[u];
  float a[4] = {v.x, v.y, v.z, v.w};
  unsigned short rh[4], rm[4];
#pragma unroll
  for (int i = 0; i < 4; ++i) {
    rh[i] = bf16_rne(a[i]);
    rm[i] = bf16_rne(__fsub_rn(a[i], bf16f(rh[i])));
  }
  ushort4 oh = {rh[0], rh[1], rh[2], rh[3]};
  ushort4 om = {rm[0], rm[1], rm[2], rm[3]};
  ((ushort4*)w_hi)[u] = oh;
  ((ushort4*)w_mid)[u] = om;
}

// ---- MFMA score + argmax: grid (64 n-tiles, 16 k-slices), kc-loop x4 ----
__global__ __launch_bounds__(256, 2) void vq_score_mfma(
    const unsigned short* __restrict__ ah, const unsigned short* __restrict__ am,
    const unsigned short* __restrict__ wh, const unsigned short* __restrict__ wm,
    const float* __restrict__ gumbel, const float* __restrict__ Arow,
    float2* __restrict__ cand) {
  // Double-buffered staging: [buf][comp][row][d32]. 32 KiB each, 64 KiB total.
  __shared__ unsigned short sA[2][2][128][32];
  __shared__ unsigned short sW[2][2][128][32];

  const int tid = threadIdx.x;
  const int wv = tid >> 6, lane = tid & 63;
  const int r16 = lane & 15, q = lane >> 4;
  const int wrow = (wv & 1) * 64, wcol = (wv >> 1) * 64;
  const int n0 = blockIdx.x * 128;
  const int kbase = blockIdx.y * 512;
  const int sw = (r16 & 3) ^ ((r16 >> 2) & 1);  // read-side chunk swizzle
  // glds lane->global map (write side): page-local row rp, phys chunk pc
  const int rp = lane >> 2, pc = lane & 3;
  const int lc = pc ^ ((rp & 3) ^ ((rp >> 2) & 1));  // logical chunk fetched

  float Av[4][4], bv[4][4];
  int bk[4][4];
#pragma unroll
  for (int i = 0; i < 4; ++i)
#pragma unroll
    for (int rg = 0; rg < 4; ++rg) {
      Av[i][rg] = Arow[n0 + wrow + i * 16 + q * 4 + rg];
      bv[i][rg] = -3.4e38f;
      bk[i][rg] = 0x7fffffff;
    }

  float gpre[4][4][4];  // gumbel prefetch for the CURRENT kc (issued 1 kc early)

  auto stage = [&](int buf, int k0s, int d0) {
    // 32 pages of 1KB: wave wv stages pages gi=wv*8..wv*8+7
#pragma unroll
    for (int t = 0; t < 8; ++t) {
      const int gi = wv * 8 + t;
      const int m = gi >> 4, c = (gi >> 3) & 1, p = gi & 7;
      const unsigned short* gsrc = (m == 0) ? (c == 0 ? ah : am)
                                            : (c == 0 ? wh : wm);
      const int grow_ = ((m == 0) ? n0 : k0s) + p * 16 + rp;
      const void* ga = gsrc + (size_t)grow_ * 256 + d0 + lc * 8;
      void* la = (m == 0) ? (void*)&sA[buf][c][p * 16][0]
                          : (void*)&sW[buf][c][p * 16][0];
      glds16(ga, la);
    }
  };
  auto pre_g = [&](int k0s) {
#pragma unroll
    for (int i = 0; i < 4; ++i)
#pragma unroll
      for (int rg = 0; rg < 4; ++rg) {
        const float* grow =
            gumbel + (size_t)(n0 + wrow + i * 16 + q * 4 + rg) * 8192 + k0s +
            wcol + r16;
#pragma unroll
        for (int j = 0; j < 4; ++j) gpre[i][rg][j] = grow[j * 16];
      }
  };

  // prologue: stage (kc=0,dc=0) into buf0, prefetch kc=0 gumbel, drain once.
  stage(0, kbase, 0);
  pre_g(kbase);
  asm volatile("s_waitcnt vmcnt(0)" ::: "memory");
  __builtin_amdgcn_s_barrier();
  asm volatile("" ::: "memory");

#pragma unroll 1
  for (int kc = 0; kc < 4; ++kc) {
    const int k0 = kbase + kc * 128;
    floatx4 acc[4][4];
#pragma unroll
    for (int i = 0; i < 4; ++i)
#pragma unroll
      for (int j = 0; j < 4; ++j) acc[i][j] = (floatx4){0.f, 0.f, 0.f, 0.f};

#pragma unroll
    for (int dc = 0; dc < 8; ++dc) {
      const int buf = dc & 1;  // each kc starts at buf 0 (8 flips per kc)
      // phase start: issue NEXT tile's staging into buf^1 (in flight through
      // the MFMA cluster; buf^1 was last read at dc-1, protected by barrier)
      if (dc < 7) {
        stage(buf ^ 1, k0, (dc + 1) * 32);
      } else if (kc < 3) {
        stage(buf ^ 1, k0 + 128, 0);
      }
      // frags from current buffer (compiler-managed lgkmcnt before MFMA use)
      bf16x8 af[2][4], bf[2][4];
#pragma unroll
      for (int c = 0; c < 2; ++c)
#pragma unroll
        for (int i = 0; i < 4; ++i) {
          af[c][i] = *(const bf16x8*)&sA[buf][c][wrow + i * 16 + r16][(q ^ sw) * 8];
          bf[c][i] = *(const bf16x8*)&sW[buf][c][wcol + i * 16 + r16][(q ^ sw) * 8];
        }
      __builtin_amdgcn_s_setprio(1);
#pragma unroll
      for (int i = 0; i < 4; ++i)
#pragma unroll
        for (int j = 0; j < 4; ++j) {
          floatx4 a = acc[i][j];
          a = __builtin_amdgcn_mfma_f32_16x16x32_bf16(af[1][i], bf[1][j], a, 0, 0, 0);
          a = __builtin_amdgcn_mfma_f32_16x16x32_bf16(af[1][i], bf[0][j], a, 0, 0, 0);
          a = __builtin_amdgcn_mfma_f32_16x16x32_bf16(af[0][i], bf[1][j], a, 0, 0, 0);
          a = __builtin_amdgcn_mfma_f32_16x16x32_bf16(af[0][i], bf[0][j], a, 0, 0, 0);
          acc[i][j] = a;
        }
      __builtin_amdgcn_s_setprio(0);
      // phase end: next buffer's staging (issued a full MFMA cluster ago) must
      // have landed; single drain + raw barrier (no compiler full-drain).
      asm volatile("s_waitcnt vmcnt(0)" ::: "memory");
      __builtin_amdgcn_s_barrier();
      asm volatile("" ::: "memory");
    }

    // per-kc epilogue: s = fl(g - fl(A - M)); running first-occurrence argmax
#pragma unroll
    for (int i = 0; i < 4; ++i)
#pragma unroll
      for (int rg = 0; rg < 4; ++rg) {
#pragma unroll
        for (int j = 0; j < 4; ++j) {  // ascending k
          const float t2 = __fsub_rn(Av[i][rg], acc[i][j][rg]);
          const float s = __fsub_rn(gpre[i][rg][j], t2);
          const int kk = k0 + wcol + j * 16 + r16;
          if (s > bv[i][rg]) { bv[i][rg] = s; bk[i][rg] = kk; }
        }
      }
    // issue next kc's gumbel loads now: they have the whole next kc to land
    if (kc < 3) pre_g(k0 + 128);
  }

  // reduce across the 16 lanes sharing a token row (r16 = col dimension).
  // red overlays sW[0] (dead after the last phase barrier): 2 KiB of 32 KiB.
  float2* redp = (float2*)&sW[0][0][0][0];
#pragma unroll
  for (int i = 0; i < 4; ++i)
#pragma unroll
    for (int rg = 0; rg < 4; ++rg) {
      float v = bv[i][rg];
      int kkk = bk[i][rg];
#pragma unroll
      for (int m = 1; m < 16; m <<= 1) {
        const float ov = __shfl_xor(v, m, 64);
        const int ok = __shfl_xor(kkk, m, 64);
        if (ov > v || (ov == v && ok < kkk)) { v = ov; kkk = ok; }
      }
      if (r16 == 0)
        redp[(wrow + i * 16 + q * 4 + rg) * 2 + (wv >> 1)] = make_float2(v, (float)kkk);
    }
  __syncthreads();
  if (tid < 128) {
    float2 bb = redp[tid * 2 + 0];  // lower-k half first: first-occurrence ties
    const float2 c = redp[tid * 2 + 1];
    if (c.x > bb.x || (c.x == bb.x && c.y < bb.y)) bb = c;
    cand[(size_t)blockIdx.y * 8192 + n0 + tid] = bb;  // slice-major
  }
}

// ---- reduce 16 slice-candidates per token (coalesced slice-major reads) ----
__global__ void vq_reduce_cand(const float2* __restrict__ cand, int* __restrict__ idxbuf,
                               int* __restrict__ hist, float* __restrict__ out_idx) {
  const int n = blockIdx.x * 256 + threadIdx.x;
  float2 b = cand[n];
#pragma unroll
  for (int s = 1; s < 16; ++s) {  // ascending-k slices
    const float2 c = cand[(size_t)s * 8192 + n];
    if (c.x > b.x || (c.x == b.x && c.y < b.y)) b = c;
  }
  const int k = (int)b.y;
  idxbuf[n] = k;
  out_idx[n] = b.y;
  atomicAdd(&hist[k], 1);
}

// ---- gather z_q, STE output (NCHW), loss partials (512 blocks) ----
__global__ void vq_gather_out(const float* __restrict__ z_e, const float* __restrict__ weight,
                              const int* __restrict__ idxbuf, float* __restrict__ out0,
                              float* __restrict__ lpart) {
  __shared__ int sidx[32];
  __shared__ float sred[256];
  const int bx2 = blockIdx.x;
  const int bx = bx2 >> 1, half = bx2 & 1;
  const int b = bx >> 5, h = bx & 31;
  const int tid = threadIdx.x;
  if (tid < 32) sidx[tid] = idxbuf[bx * 32 + tid];
  __syncthreads();
  const int w = tid & 31, dg = tid >> 5;
  const int srow = sidx[w];
  const size_t base = (size_t)b * (256 * 1024) + (size_t)h * 32 + w;
  float part = 0.f;
#pragma unroll 4
  for (int it = 0; it < 16; ++it) {
    const int d = half * 128 + dg * 16 + it;
    const float qv = weight[(size_t)srow * 256 + d];
    const size_t a = base + (size_t)d * 1024;
    const float ze = z_e[a];
    const float df = qv - ze;
    out0[a] = ze + df;  // fl(ze + fl(q - ze)) per reference STE
    part = fmaf(df, df, part);
  }
  sred[tid] = part;
  __syncthreads();
#pragma unroll
  for (int off = 128; off > 0; off >>= 1) {
    if (tid < off) sred[tid] += sred[tid + off];
    __syncthreads();
  }
  if (tid == 0) lpart[bx2] = sred[0];
}

// ---- scalars: vq_loss, perplexity ----
__global__ void vq_finalize(const float* __restrict__ lpart, const int* __restrict__ hist,
                            float* __restrict__ out) {
  __shared__ double sd[256];
  const int tid = threadIdx.x;
  sd[tid] = (double)lpart[tid] + (double)lpart[tid + 256];
  __syncthreads();
#pragma unroll
  for (int off = 128; off > 0; off >>= 1) {
    if (tid < off) sd[tid] += sd[tid + off];
    __syncthreads();
  }
  if (tid == 0) out[2097152] = (float)(1.25 * sd[0] / 2097152.0);
  __syncthreads();
  double hh = 0.0;
#pragma unroll 4
  for (int qq = 0; qq < 32; ++qq) {
    const int c = hist[tid * 32 + qq];
    const double p = (double)c / 8192.0;
    hh += p * log(p + 1e-10);
  }
  sd[tid] = hh;
  __syncthreads();
#pragma unroll
  for (int off = 128; off > 0; off >>= 1) {
    if (tid < off) sd[tid] += sd[tid + off];
    __syncthreads();
  }
  if (tid == 0) out[2097153] = (float)exp(-sd[0]);
}

extern "C" void kernel_launch(void* const* d_in, const int* in_sizes, int n_in,
                              void* d_out, int out_size, void* d_ws, size_t ws_size,
                              hipStream_t stream) {
  const float* z_e = (const float*)d_in[0];     // [8,256,32,32]
  const float* weight = (const float*)d_in[1];  // [8192,256]
  const float* gumbel = (const float*)d_in[2];  // [8192,8192]
  float* out = (float*)d_out;  // [z_q_ste 2097152][vq_loss][perplexity][indices 8192]

  float* ws = (float*)d_ws;
  float* Arow = ws;                         // 8192 f
  int* hist = (int*)(ws + 8192);            // 8192 i
  float* lpart = ws + 16384;                // 512 f
  int* idxbuf = (int*)(ws + 16896);         // 8192 i
  float2* cand = (float2*)(ws + 25088);     // 16*8192 float2 = 262144 f
  unsigned short* sb = (unsigned short*)(ws + 25088 + 262144);
  unsigned short* a_hi = sb;                // 4 x 8192*256 shorts (4MB each)
  unsigned short* a_mid = sb + 2097152;
  unsigned short* w_hi = sb + 2 * 2097152;
  unsigned short* w_mid = sb + 3 * 2097152;

  hipMemsetAsync(hist, 0, 8192 * sizeof(int), stream);
  vq_prep_a<<<256, 256, 0, stream>>>(z_e, a_hi, a_mid, Arow);
  vq_prep_w<<<2048, 256, 0, stream>>>(weight, w_hi, w_mid);
  vq_score_mfma<<<dim3(64, 16), 256, 0, stream>>>(a_hi, a_mid, w_hi, w_mid,
                                                  gumbel, Arow, cand);
  vq_reduce_cand<<<32, 256, 0, stream>>>(cand, idxbuf, hist, out + 2097154);
  vq_gather_out<<<512, 256, 0, stream>>>(z_e, weight, idxbuf, out, lpart);
  vq_finalize<<<1, 256, 0, stream>>>(lpart, hist, out);
}

// Round 2
// 642.668 us; speedup vs baseline: 1.0699x; 1.0699x over previous
//
#include <hip/hip_runtime.h>
#include <math.h>

// N=B*H*W=8192 tokens, K=8192 codes, D=256 dims.
// Numerics (bit-exact vs np in rounds 2-3): first-occurrence argmax over k of
//   s = fl(g - fl(A_n - M_nk)), A_n = numpy-pairwise fp32 sum of fl(f^2),
//   M = (2f)@W^T. Round 4: 4-pass split-bf16 MFMA (hi/mid), global_load_lds
//   staging, XOR-swizzled unpadded LDS, kc-loop.
// Round 5 (regressed, diagnosed): full-unroll + 64-VGPR gumbel prefetch ->
//   scratch spills (WRITE_SIZE 1MB->137MB). Round 6: pipeline ONLY —
//   double-buffered LDS, stage(next) issued before compute, one raw
//   s_barrier + inline vmcnt(0) per phase, setprio around MFMA. dc loop kept
//   at unroll 1 (runtime buf only feeds LDS address math, not reg indexing);
//   epilogue gumbel loads direct (round-4 code). Same MFMA order/rounding ->
//   bit-identical outputs.

typedef __attribute__((ext_vector_type(8))) short bf16x8;
typedef __attribute__((ext_vector_type(4))) float floatx4;

__device__ __forceinline__ float sq025(float q) {
  return __fmul_rn(__fmul_rn(q, q), 0.25f);
}
__device__ __forceinline__ unsigned short bf16_rne(float x) {
  unsigned int u = __float_as_uint(x);
  return (unsigned short)((u + 0x7FFFu + ((u >> 16) & 1u)) >> 16);
}
__device__ __forceinline__ float bf16f(unsigned short h) {
  return __uint_as_float(((unsigned int)h) << 16);
}
__device__ __forceinline__ void glds16(const void* g, void* l) {
  __builtin_amdgcn_global_load_lds(
      (const __attribute__((address_space(1))) unsigned int*)g,
      (__attribute__((address_space(3))) unsigned int*)l, 16, 0, 0);
}

// ---- prep A: z_e (NCHW) -> a_hi/a_mid (split of q=2z, [n][d]) + Arow ----
__global__ void vq_prep_a(const float* __restrict__ z_e,
                          unsigned short* __restrict__ a_hi,
                          unsigned short* __restrict__ a_mid,
                          float* __restrict__ Arow) {
  __shared__ float tile[256][36];
  const int bx = blockIdx.x;  // b*32 + h
  const int b = bx >> 5, h = bx & 31;
  const int tid = threadIdx.x;
  const int w = tid & 31, dg = tid >> 5;
  const size_t zbase = (size_t)b * (256 * 1024) + (size_t)h * 32;
#pragma unroll 4
  for (int it = 0; it < 32; ++it) {
    const int d = dg * 32 + it;
    tile[d][w] = 2.0f * z_e[zbase + (size_t)d * 1024 + w];  // q = 2f, exact
  }
  __syncthreads();
  const int n0 = bx * 32;
#pragma unroll 4
  for (int w2 = 0; w2 < 32; ++w2) {
    const float q = tile[tid][w2];
    const unsigned short hh = bf16_rne(q);
    const float r1 = __fsub_rn(q, bf16f(hh));
    a_hi[(size_t)(n0 + w2) * 256 + tid] = hh;
    a_mid[(size_t)(n0 + w2) * 256 + tid] = bf16_rne(r1);
  }
  // numpy-pairwise ||f||^2 from q=2f (verified bit-exact in r2/r3)
  const int tg = tid >> 3, j = tid & 7;
  float halfs[2];
#pragma unroll
  for (int hf = 0; hf < 2; ++hf) {
    float r = sq025(tile[hf * 128 + j][tg]);
#pragma unroll
    for (int i = 1; i < 16; ++i)
      r = __fadd_rn(r, sq025(tile[hf * 128 + 8 * i + j][tg]));
    const float t2 = __fadd_rn(r, __shfl_xor(r, 1, 64));
    const float t4 = __fadd_rn(t2, __shfl_xor(t2, 2, 64));
    halfs[hf] = __fadd_rn(t4, __shfl_xor(t4, 4, 64));
  }
  if (j == 0) Arow[n0 + tg] = __fadd_rn(halfs[0], halfs[1]);
}

// ---- prep W: weight -> w_hi/w_mid ----
__global__ void vq_prep_w(const float* __restrict__ weight,
                          unsigned short* __restrict__ w_hi,
                          unsigned short* __restrict__ w_mid) {
  const int u = blockIdx.x * 256 + threadIdx.x;  // float4 idx, 524288 total
  const float4 v = ((const float4*)weight)[u];
  float a[4] = {v.x, v.y, v.z, v.w};
  unsigned short rh[4], rm[4];
#pragma unroll
  for (int i = 0; i < 4; ++i) {
    rh[i] = bf16_rne(a[i]);
    rm[i] = bf16_rne(__fsub_rn(a[i], bf16f(rh[i])));
  }
  ushort4 oh = {rh[0], rh[1], rh[2], rh[3]};
  ushort4 om = {rm[0], rm[1], rm[2], rm[3]};
  ((ushort4*)w_hi)[u] = oh;
  ((ushort4*)w_mid)[u] = om;
}

// ---- MFMA score + argmax: grid (64 n-tiles, 16 k-slices), kc-loop x4 ----
__global__ __launch_bounds__(256, 2) void vq_score_mfma(
    const unsigned short* __restrict__ ah, const unsigned short* __restrict__ am,
    const unsigned short* __restrict__ wh, const unsigned short* __restrict__ wm,
    const float* __restrict__ gumbel, const float* __restrict__ Arow,
    float2* __restrict__ cand) {
  // Double-buffered staging: [buf][comp][row][d32]. 32 KiB each, 64 KiB total.
  __shared__ unsigned short sA[2][2][128][32];
  __shared__ unsigned short sW[2][2][128][32];

  const int tid = threadIdx.x;
  const int wv = tid >> 6, lane = tid & 63;
  const int r16 = lane & 15, q = lane >> 4;
  const int wrow = (wv & 1) * 64, wcol = (wv >> 1) * 64;
  const int n0 = blockIdx.x * 128;
  const int kbase = blockIdx.y * 512;
  const int sw = (r16 & 3) ^ ((r16 >> 2) & 1);  // read-side chunk swizzle
  // glds lane->global map (write side): page-local row rp, phys chunk pc
  const int rp = lane >> 2, pc = lane & 3;
  const int lc = pc ^ ((rp & 3) ^ ((rp >> 2) & 1));  // logical chunk fetched

  float Av[4][4], bv[4][4];
  int bk[4][4];
#pragma unroll
  for (int i = 0; i < 4; ++i)
#pragma unroll
    for (int rg = 0; rg < 4; ++rg) {
      Av[i][rg] = Arow[n0 + wrow + i * 16 + q * 4 + rg];
      bv[i][rg] = -3.4e38f;
      bk[i][rg] = 0x7fffffff;
    }

  auto stage = [&](int buf, int k0s, int d0) {
    // 32 pages of 1KB: wave wv stages pages gi=wv*8..wv*8+7
#pragma unroll
    for (int t = 0; t < 8; ++t) {
      const int gi = wv * 8 + t;
      const int m = gi >> 4, c = (gi >> 3) & 1, p = gi & 7;
      const unsigned short* gsrc = (m == 0) ? (c == 0 ? ah : am)
                                            : (c == 0 ? wh : wm);
      const int grow_ = ((m == 0) ? n0 : k0s) + p * 16 + rp;
      const void* ga = gsrc + (size_t)grow_ * 256 + d0 + lc * 8;
      void* la = (m == 0) ? (void*)&sA[buf][c][p * 16][0]
                          : (void*)&sW[buf][c][p * 16][0];
      glds16(ga, la);
    }
  };

  // prologue: stage (kc=0,dc=0) into buf0, drain once.
  stage(0, kbase, 0);
  asm volatile("s_waitcnt vmcnt(0)" ::: "memory");
  __builtin_amdgcn_s_barrier();
  asm volatile("" ::: "memory");

#pragma unroll 1
  for (int kc = 0; kc < 4; ++kc) {
    const int k0 = kbase + kc * 128;
    floatx4 acc[4][4];
#pragma unroll
    for (int i = 0; i < 4; ++i)
#pragma unroll
      for (int j = 0; j < 4; ++j) acc[i][j] = (floatx4){0.f, 0.f, 0.f, 0.f};

#pragma unroll 1
    for (int dc = 0; dc < 8; ++dc) {
      const int buf = dc & 1;  // each kc starts at buf 0 (8 flips per kc)
      // phase start: issue NEXT tile's staging into buf^1 (in flight through
      // the MFMA cluster; buf^1's readers finished at the dc-1 barrier)
      if (dc < 7) {
        stage(buf ^ 1, k0, (dc + 1) * 32);
      } else if (kc < 3) {
        stage(buf ^ 1, k0 + 128, 0);
      }
      // frags from current buffer (compiler-managed lgkmcnt before MFMA use)
      bf16x8 af[2][4], bf[2][4];
#pragma unroll
      for (int c = 0; c < 2; ++c)
#pragma unroll
        for (int i = 0; i < 4; ++i) {
          af[c][i] = *(const bf16x8*)&sA[buf][c][wrow + i * 16 + r16][(q ^ sw) * 8];
          bf[c][i] = *(const bf16x8*)&sW[buf][c][wcol + i * 16 + r16][(q ^ sw) * 8];
        }
      __builtin_amdgcn_s_setprio(1);
#pragma unroll
      for (int i = 0; i < 4; ++i)
#pragma unroll
        for (int j = 0; j < 4; ++j) {
          floatx4 a = acc[i][j];
          a = __builtin_amdgcn_mfma_f32_16x16x32_bf16(af[1][i], bf[1][j], a, 0, 0, 0);
          a = __builtin_amdgcn_mfma_f32_16x16x32_bf16(af[1][i], bf[0][j], a, 0, 0, 0);
          a = __builtin_amdgcn_mfma_f32_16x16x32_bf16(af[0][i], bf[1][j], a, 0, 0, 0);
          a = __builtin_amdgcn_mfma_f32_16x16x32_bf16(af[0][i], bf[0][j], a, 0, 0, 0);
          acc[i][j] = a;
        }
      __builtin_amdgcn_s_setprio(0);
      // phase end: next buffer's staging (issued a full MFMA cluster ago) must
      // have landed; single drain + raw barrier (no compiler full-drain).
      asm volatile("s_waitcnt vmcnt(0)" ::: "memory");
      __builtin_amdgcn_s_barrier();
      asm volatile("" ::: "memory");
    }

    // per-kc epilogue: s = fl(g - fl(A - M)); running first-occurrence argmax
#pragma unroll
    for (int i = 0; i < 4; ++i)
#pragma unroll
      for (int rg = 0; rg < 4; ++rg) {
        const int nloc = wrow + i * 16 + q * 4 + rg;
        const float* grow = gumbel + (size_t)(n0 + nloc) * 8192 + k0 + wcol + r16;
#pragma unroll
        for (int j = 0; j < 4; ++j) {  // ascending k
          const float t2 = __fsub_rn(Av[i][rg], acc[i][j][rg]);
          const float s = __fsub_rn(grow[j * 16], t2);
          const int kk = k0 + wcol + j * 16 + r16;
          if (s > bv[i][rg]) { bv[i][rg] = s; bk[i][rg] = kk; }
        }
      }
  }

  // reduce across the 16 lanes sharing a token row (r16 = col dimension).
  // red overlays sW[0] (dead after the last phase barrier): 2 KiB of 32 KiB.
  float2* redp = (float2*)&sW[0][0][0][0];
#pragma unroll
  for (int i = 0; i < 4; ++i)
#pragma unroll
    for (int rg = 0; rg < 4; ++rg) {
      float v = bv[i][rg];
      int kkk = bk[i][rg];
#pragma unroll
      for (int m = 1; m < 16; m <<= 1) {
        const float ov = __shfl_xor(v, m, 64);
        const int ok = __shfl_xor(kkk, m, 64);
        if (ov > v || (ov == v && ok < kkk)) { v = ov; kkk = ok; }
      }
      if (r16 == 0)
        redp[(wrow + i * 16 + q * 4 + rg) * 2 + (wv >> 1)] = make_float2(v, (float)kkk);
    }
  __syncthreads();
  if (tid < 128) {
    float2 bb = redp[tid * 2 + 0];  // lower-k half first: first-occurrence ties
    const float2 c = redp[tid * 2 + 1];
    if (c.x > bb.x || (c.x == bb.x && c.y < bb.y)) bb = c;
    cand[(size_t)blockIdx.y * 8192 + n0 + tid] = bb;  // slice-major
  }
}

// ---- reduce 16 slice-candidates per token (coalesced slice-major reads) ----
__global__ void vq_reduce_cand(const float2* __restrict__ cand, int* __restrict__ idxbuf,
                               int* __restrict__ hist, float* __restrict__ out_idx) {
  const int n = blockIdx.x * 256 + threadIdx.x;
  float2 b = cand[n];
#pragma unroll
  for (int s = 1; s < 16; ++s) {  // ascending-k slices
    const float2 c = cand[(size_t)s * 8192 + n];
    if (c.x > b.x || (c.x == b.x && c.y < b.y)) b = c;
  }
  const int k = (int)b.y;
  idxbuf[n] = k;
  out_idx[n] = b.y;
  atomicAdd(&hist[k], 1);
}

// ---- gather z_q, STE output (NCHW), loss partials (512 blocks) ----
__global__ void vq_gather_out(const float* __restrict__ z_e, const float* __restrict__ weight,
                              const int* __restrict__ idxbuf, float* __restrict__ out0,
                              float* __restrict__ lpart) {
  __shared__ int sidx[32];
  __shared__ float sred[256];
  const int bx2 = blockIdx.x;
  const int bx = bx2 >> 1, half = bx2 & 1;
  const int b = bx >> 5, h = bx & 31;
  const int tid = threadIdx.x;
  if (tid < 32) sidx[tid] = idxbuf[bx * 32 + tid];
  __syncthreads();
  const int w = tid & 31, dg = tid >> 5;
  const int srow = sidx[w];
  const size_t base = (size_t)b * (256 * 1024) + (size_t)h * 32 + w;
  float part = 0.f;
#pragma unroll 4
  for (int it = 0; it < 16; ++it) {
    const int d = half * 128 + dg * 16 + it;
    const float qv = weight[(size_t)srow * 256 + d];
    const size_t a = base + (size_t)d * 1024;
    const float ze = z_e[a];
    const float df = qv - ze;
    out0[a] = ze + df;  // fl(ze + fl(q - ze)) per reference STE
    part = fmaf(df, df, part);
  }
  sred[tid] = part;
  __syncthreads();
#pragma unroll
  for (int off = 128; off > 0; off >>= 1) {
    if (tid < off) sred[tid] += sred[tid + off];
    __syncthreads();
  }
  if (tid == 0) lpart[bx2] = sred[0];
}

// ---- scalars: vq_loss, perplexity ----
__global__ void vq_finalize(const float* __restrict__ lpart, const int* __restrict__ hist,
                            float* __restrict__ out) {
  __shared__ double sd[256];
  const int tid = threadIdx.x;
  sd[tid] = (double)lpart[tid] + (double)lpart[tid + 256];
  __syncthreads();
#pragma unroll
  for (int off = 128; off > 0; off >>= 1) {
    if (tid < off) sd[tid] += sd[tid + off];
    __syncthreads();
  }
  if (tid == 0) out[2097152] = (float)(1.25 * sd[0] / 2097152.0);
  __syncthreads();
  double hh = 0.0;
#pragma unroll 4
  for (int qq = 0; qq < 32; ++qq) {
    const int c = hist[tid * 32 + qq];
    const double p = (double)c / 8192.0;
    hh += p * log(p + 1e-10);
  }
  sd[tid] = hh;
  __syncthreads();
#pragma unroll
  for (int off = 128; off > 0; off >>= 1) {
    if (tid < off) sd[tid] += sd[tid + off];
    __syncthreads();
  }
  if (tid == 0) out[2097153] = (float)exp(-sd[0]);
}

extern "C" void kernel_launch(void* const* d_in, const int* in_sizes, int n_in,
                              void* d_out, int out_size, void* d_ws, size_t ws_size,
                              hipStream_t stream) {
  const float* z_e = (const float*)d_in[0];     // [8,256,32,32]
  const float* weight = (const float*)d_in[1];  // [8192,256]
  const float* gumbel = (const float*)d_in[2];  // [8192,8192]
  float* out = (float*)d_out;  // [z_q_ste 2097152][vq_loss][perplexity][indices 8192]

  float* ws = (float*)d_ws;
  float* Arow = ws;                         // 8192 f
  int* hist = (int*)(ws + 8192);            // 8192 i
  float* lpart = ws + 16384;                // 512 f
  int* idxbuf = (int*)(ws + 16896);         // 8192 i
  float2* cand = (float2*)(ws + 25088);     // 16*8192 float2 = 262144 f
  unsigned short* sb = (unsigned short*)(ws + 25088 + 262144);
  unsigned short* a_hi = sb;                // 4 x 8192*256 shorts (4MB each)
  unsigned short* a_mid = sb + 2097152;
  unsigned short* w_hi = sb + 2 * 2097152;
  unsigned short* w_mid = sb + 3 * 2097152;

  hipMemsetAsync(hist, 0, 8192 * sizeof(int), stream);
  vq_prep_a<<<256, 256, 0, stream>>>(z_e, a_hi, a_mid, Arow);
  vq_prep_w<<<2048, 256, 0, stream>>>(weight, w_hi, w_mid);
  vq_score_mfma<<<dim3(64, 16), 256, 0, stream>>>(a_hi, a_mid, w_hi, w_mid,
                                                  gumbel, Arow, cand);
  vq_reduce_cand<<<32, 256, 0, stream>>>(cand, idxbuf, hist, out + 2097154);
  vq_gather_out<<<512, 256, 0, stream>>>(z_e, weight, idxbuf, out, lpart);
  vq_finalize<<<1, 256, 0, stream>>>(lpart, hist, out);
}